// Round 1
// baseline (2719.019 us; speedup 1.0000x reference)
//
#include <hip/hip_runtime.h>
#include <hip/hip_bf16.h>

// Problem constants (from reference)
#define NN 50000
#define EE 800000
#define INF_ 128
#define HH 4
#define FF 32
#define HF 128          // H*F
#define OUTC 160        // (H+1)*F per node
#define NEG_SLOPE 0.2f

// ---------------- monotonic float<->uint encoding for atomicMax ----------------
__device__ __forceinline__ unsigned enc_f(float f) {
    unsigned u = __float_as_uint(f);
    return (u & 0x80000000u) ? ~u : (u | 0x80000000u);
}
__device__ __forceinline__ float dec_f(unsigned e) {
    unsigned u = (e & 0x80000000u) ? (e & 0x7FFFFFFFu) : ~e;
    return __uint_as_float(u);
}

// ---------------- init: zero d_out, smax(enc)=0, denom=0 ----------------
__global__ void init_kernel(float* __restrict__ out, unsigned* __restrict__ smax,
                            float* __restrict__ denom, int out_size) {
    int idx = blockIdx.x * blockDim.x + threadIdx.x;
    if (idx < out_size) out[idx] = 0.f;
    if (idx < NN * HH) { smax[idx] = 0u; denom[idx] = 0.f; }
}

// ---------------- fused projection GEMM: [N,128] x [128,416] ----------------
// col tiles: 0-3 -> W_src_mut (el_mut), 4-7 -> W_dst_mut (er_mut),
//            8-11 -> W_self (el_self), 12 -> W_lin (-> d_out feat_lin slot)
__global__ __launch_bounds__(256) void proj_gemm(
    const float* __restrict__ feat,
    const float* __restrict__ W0, const float* __restrict__ b0,
    const float* __restrict__ W1, const float* __restrict__ b1,
    const float* __restrict__ W2, const float* __restrict__ b2,
    const float* __restrict__ W3, const float* __restrict__ b3,
    float* __restrict__ el_mut, float* __restrict__ er_mut,
    float* __restrict__ el_self, float* __restrict__ out)
{
    __shared__ __align__(16) float As[32][128];
    __shared__ float Bs[128][33];

    const int tile = blockIdx.y;          // 0..12
    const int row0 = blockIdx.x * 32;
    const int tid  = threadIdx.x;

    const float* W; const float* bias; int ldw; int colOff;
    if (tile < 4)       { W = W0; bias = b0; ldw = 128; colOff = tile * 32; }
    else if (tile < 8)  { W = W1; bias = b1; ldw = 128; colOff = (tile - 4) * 32; }
    else if (tile < 12) { W = W2; bias = b2; ldw = 128; colOff = (tile - 8) * 32; }
    else                { W = W3; bias = b3; ldw = 32;  colOff = 0; }

    // stage A tile 32x128
    for (int i = tid; i < 32 * 128; i += 256) {
        int r = i >> 7, k = i & 127;
        int grow = row0 + r;
        As[r][k] = (grow < NN) ? feat[grow * INF_ + k] : 0.f;
    }
    // stage B tile 128x32
    for (int i = tid; i < 128 * 32; i += 256) {
        int k = i >> 5, c = i & 31;
        Bs[k][c] = W[k * ldw + colOff + c];
    }
    __syncthreads();

    const int col = tid & 31;
    const int rg  = tid >> 5;             // 0..7
    float acc0 = 0.f, acc1 = 0.f, acc2 = 0.f, acc3 = 0.f;

    const float4* A0 = (const float4*)As[rg];
    const float4* A1 = (const float4*)As[rg + 8];
    const float4* A2 = (const float4*)As[rg + 16];
    const float4* A3 = (const float4*)As[rg + 24];

    #pragma unroll
    for (int k4 = 0; k4 < 32; ++k4) {
        float4 a0 = A0[k4], a1 = A1[k4], a2 = A2[k4], a3 = A3[k4];
        float bv0 = Bs[k4 * 4 + 0][col];
        float bv1 = Bs[k4 * 4 + 1][col];
        float bv2 = Bs[k4 * 4 + 2][col];
        float bv3 = Bs[k4 * 4 + 3][col];
        acc0 += a0.x * bv0 + a0.y * bv1 + a0.z * bv2 + a0.w * bv3;
        acc1 += a1.x * bv0 + a1.y * bv1 + a1.z * bv2 + a1.w * bv3;
        acc2 += a2.x * bv0 + a2.y * bv1 + a2.z * bv2 + a2.w * bv3;
        acc3 += a3.x * bv0 + a3.y * bv1 + a3.z * bv2 + a3.w * bv3;
    }

    float bb = bias[colOff + col];
    float accs[4] = {acc0, acc1, acc2, acc3};
    #pragma unroll
    for (int j = 0; j < 4; ++j) {
        int grow = row0 + rg + j * 8;
        if (grow >= NN) continue;
        float v = accs[j] + bb;
        if (tile < 4)       el_mut[grow * HF + colOff + col] = v;
        else if (tile < 8)  er_mut[grow * HF + colOff + col] = v;
        else if (tile < 12) el_self[grow * HF + colOff + col] = v;
        else                out[grow * OUTC + col] = v;   // feat_lin slot
    }
}

// ---------------- edge scores + segment max ----------------
// 2 edges per 256-thread block; 128 threads per edge (i = h*32+f)
__global__ __launch_bounds__(256) void edge_score(
    const float* __restrict__ el_mut, const float* __restrict__ er_mut,
    const float* __restrict__ attn,
    const int* __restrict__ src, const int* __restrict__ dst,
    float* __restrict__ s_arr, unsigned* __restrict__ smax)
{
    int tid = threadIdx.x;
    long long e = (long long)blockIdx.x * 2 + (tid >> 7);
    if (e >= EE) return;
    int i = tid & 127;            // h*32 + f
    int h = i >> 5;
    int sn = src[e];
    int dn = dst[e];
    float v = el_mut[(long long)sn * HF + i] + er_mut[(long long)dn * HF + i];
    v = (v > 0.f) ? v : NEG_SLOPE * v;
    v *= attn[i];
    // reduce over 32 lanes (f dimension)
    #pragma unroll
    for (int off = 16; off > 0; off >>= 1)
        v += __shfl_down(v, off, 32);
    if ((i & 31) == 0) {
        s_arr[e * HH + h] = v;
        atomicMax(&smax[(long long)dn * HH + h], enc_f(v));
    }
}

// ---------------- exp + denom ----------------
__global__ __launch_bounds__(256) void edge_exp(
    float* __restrict__ s_arr, const unsigned* __restrict__ smax,
    const int* __restrict__ dst, float* __restrict__ denom)
{
    long long idx = (long long)blockIdx.x * 256 + threadIdx.x;
    if (idx >= (long long)EE * HH) return;
    long long e = idx >> 2;
    int h = (int)(idx & 3);
    int dn = dst[e];
    float m = dec_f(smax[(long long)dn * HH + h]);
    float ex = __expf(s_arr[idx] - m);
    s_arr[idx] = ex;
    unsafeAtomicAdd(&denom[(long long)dn * HH + h], ex);
}

// ---------------- weighted aggregation (atomic scatter) ----------------
__global__ __launch_bounds__(256) void edge_agg(
    const float* __restrict__ el_self, const float* __restrict__ s_arr,
    const float* __restrict__ denom,
    const int* __restrict__ src, const int* __restrict__ dst,
    float* __restrict__ out)
{
    int tid = threadIdx.x;
    long long e = (long long)blockIdx.x * 2 + (tid >> 7);
    if (e >= EE) return;
    int i = tid & 127;
    int h = i >> 5;
    int sn = src[e];
    int dn = dst[e];
    float a = s_arr[e * HH + h] / denom[(long long)dn * HH + h];
    float contrib = el_self[(long long)sn * HF + i] * a;
    unsafeAtomicAdd(&out[(long long)dn * OUTC + FF + i], contrib);
}

extern "C" void kernel_launch(void* const* d_in, const int* in_sizes, int n_in,
                              void* d_out, int out_size, void* d_ws, size_t ws_size,
                              hipStream_t stream) {
    const float* feat   = (const float*)d_in[0];
    const float* W_src  = (const float*)d_in[1];
    const float* b_src  = (const float*)d_in[2];
    const float* W_dst  = (const float*)d_in[3];
    const float* b_dst  = (const float*)d_in[4];
    const float* W_self = (const float*)d_in[5];
    const float* b_self = (const float*)d_in[6];
    const float* W_lin  = (const float*)d_in[7];
    const float* b_lin  = (const float*)d_in[8];
    const float* attn   = (const float*)d_in[9];
    const int*   src    = (const int*)d_in[10];
    const int*   dst    = (const int*)d_in[11];
    float* out = (float*)d_out;

    // workspace carve-up (floats): ~91.2 MB total
    float* el_mut  = (float*)d_ws;
    float* er_mut  = el_mut  + (size_t)NN * HF;
    float* el_self = er_mut  + (size_t)NN * HF;
    float* s_arr   = el_self + (size_t)NN * HF;        // E*H
    unsigned* smax = (unsigned*)(s_arr + (size_t)EE * HH); // N*H
    float* denom   = (float*)(smax + (size_t)NN * HH);     // N*H

    // 1) init
    {
        int total = out_size;   // 8,000,000 >= N*H
        int blocks = (total + 255) / 256;
        init_kernel<<<blocks, 256, 0, stream>>>(out, smax, denom, out_size);
    }
    // 2) fused projection GEMM
    {
        dim3 grid((NN + 31) / 32, 13);
        proj_gemm<<<grid, 256, 0, stream>>>(feat,
            W_src, b_src, W_dst, b_dst, W_self, b_self, W_lin, b_lin,
            el_mut, er_mut, el_self, out);
    }
    // 3) edge scores + segment max
    edge_score<<<EE / 2, 256, 0, stream>>>(el_mut, er_mut, attn, src, dst, s_arr, smax);
    // 4) exp + denom
    edge_exp<<<(EE * HH) / 256, 256, 0, stream>>>(s_arr, smax, dst, denom);
    // 5) weighted aggregation
    edge_agg<<<EE / 2, 256, 0, stream>>>(el_self, s_arr, denom, src, dst, out);
}

// Round 2
// 821.175 us; speedup vs baseline: 3.3111x; 3.3111x over previous
//
#include <hip/hip_runtime.h>
#include <hip/hip_bf16.h>

// Problem constants (from reference)
#define NN 50000
#define EE 800000
#define INF_ 128
#define HH 4
#define FF 32
#define HF 128          // H*F
#define OUTC 160        // (H+1)*F per node
#define NEG_SLOPE 0.2f

typedef __attribute__((ext_vector_type(8))) short short8;
typedef __attribute__((ext_vector_type(4))) float f32x4;

// fp32 -> bf16 bits, round-to-nearest-even
__device__ __forceinline__ unsigned short f2bf(float f) {
    union { float f; unsigned u; } in; in.f = f;
    unsigned u = in.u;
    u += 0x7fffu + ((u >> 16) & 1u);
    return (unsigned short)(u >> 16);
}

// ---------------- monotonic float<->uint encoding for atomicMax ----------------
__device__ __forceinline__ unsigned enc_f(float f) {
    unsigned u = __float_as_uint(f);
    return (u & 0x80000000u) ? ~u : (u | 0x80000000u);
}
__device__ __forceinline__ float dec_f(unsigned e) {
    unsigned u = (e & 0x80000000u) ? (e & 0x7FFFFFFFu) : ~e;
    return __uint_as_float(u);
}

// ---------------- init: zero d_out, smax(enc)=0, denom=0 ----------------
__global__ void init_kernel(float* __restrict__ out, unsigned* __restrict__ smax,
                            float* __restrict__ denom, int out_size) {
    int idx = blockIdx.x * blockDim.x + threadIdx.x;
    if (idx < out_size) out[idx] = 0.f;
    if (idx < NN * HH) { smax[idx] = 0u; denom[idx] = 0.f; }
}

// ---------------- weight prep: concat + transpose + bf16 ----------------
// WbT[n][k] = W_concat[k][n], n in [0,416), k in [0,128)
__global__ __launch_bounds__(256) void prep_weights(
    const float* __restrict__ W0, const float* __restrict__ b0,
    const float* __restrict__ W1, const float* __restrict__ b1,
    const float* __restrict__ W2, const float* __restrict__ b2,
    const float* __restrict__ W3, const float* __restrict__ b3,
    unsigned short* __restrict__ WbT, float* __restrict__ biasc)
{
    int idx = blockIdx.x * 256 + threadIdx.x;   // 416*128 = 53248
    if (idx >= 416 * 128) return;
    int n = idx >> 7, k = idx & 127;
    float v;
    if (n < 128)      v = W0[k * 128 + n];
    else if (n < 256) v = W1[k * 128 + (n - 128)];
    else if (n < 384) v = W2[k * 128 + (n - 256)];
    else              v = W3[k * 32  + (n - 384)];
    WbT[n * 128 + k] = f2bf(v);
    if (idx < 416) {
        float bv;
        if (idx < 128)      bv = b0[idx];
        else if (idx < 256) bv = b1[idx - 128];
        else if (idx < 384) bv = b2[idx - 256];
        else                bv = b3[idx - 384];
        biasc[idx] = bv;
    }
}

// ---------------- bf16 MFMA projection GEMM ----------------
// grid (782, 2): block = 64 rows x 208 cols, 4 waves, 13 N-tiles x 4 ksteps.
// Padded LDS row stride (136 bf16 = 272 B) spreads b128 frag reads across
// bank groups (8 lanes / 4-bank group = throughput-minimal).
#define LSTRIDE 136
__global__ __launch_bounds__(256) void proj_gemm_mfma(
    const float* __restrict__ feat,
    const unsigned short* __restrict__ WbT,
    const float* __restrict__ biasc,
    float* __restrict__ el_mut, float* __restrict__ er_mut,
    float* __restrict__ el_self, float* __restrict__ out)
{
    __shared__ unsigned short As[64  * LSTRIDE];   // 17408 B
    __shared__ unsigned short Bs[208 * LSTRIDE];   // 56576 B

    const int tid  = threadIdx.x;
    const int row0 = blockIdx.x * 64;
    const int nbase = blockIdx.y * 208;

    // stage A: 64 rows x 128 fp32 -> bf16. 2048 float4 chunks, 8 per thread.
    #pragma unroll
    for (int it = 0; it < 8; ++it) {
        int f  = tid + it * 256;
        int r  = f >> 5;          // 0..63
        int k4 = f & 31;          // float4 index within row
        int grow = row0 + r;
        float4 v = make_float4(0.f, 0.f, 0.f, 0.f);
        if (grow < NN) v = ((const float4*)feat)[(size_t)grow * 32 + k4];
        unsigned p0 = (unsigned)f2bf(v.x) | ((unsigned)f2bf(v.y) << 16);
        unsigned p1 = (unsigned)f2bf(v.z) | ((unsigned)f2bf(v.w) << 16);
        uint2 pk; pk.x = p0; pk.y = p1;
        *(uint2*)&As[r * LSTRIDE + k4 * 4] = pk;
    }
    // stage B: 208 rows x 128 bf16, 8B chunks: 6656 chunks, 26 per thread.
    #pragma unroll
    for (int it = 0; it < 26; ++it) {
        int c  = tid + it * 256;
        int n  = c >> 5;          // 0..207
        int kc = c & 31;          // 8B chunk within row (32 per row)
        uint2 v = *(const uint2*)&WbT[(size_t)(nbase + n) * 128 + kc * 4];
        *(uint2*)&Bs[n * LSTRIDE + kc * 4] = v;
    }
    __syncthreads();

    const int wv   = tid >> 6;     // wave 0..3 -> rows [wv*16, wv*16+16)
    const int lane = tid & 63;
    const int m16  = lane & 15;
    const int quad = lane >> 4;

    f32x4 acc[13];
    #pragma unroll
    for (int t = 0; t < 13; ++t) acc[t] = (f32x4){0.f, 0.f, 0.f, 0.f};

    // A frags: A[m=lane&15][k=quad*8+j], k-step stride 32 elements
    short8 afr[4];
    const unsigned short* Abase = &As[(wv * 16 + m16) * LSTRIDE + quad * 8];
    #pragma unroll
    for (int ks = 0; ks < 4; ++ks)
        afr[ks] = *(const short8*)(Abase + ks * 32);

    #pragma unroll
    for (int t = 0; t < 13; ++t) {
        const unsigned short* Bbase = &Bs[(t * 16 + m16) * LSTRIDE + quad * 8];
        #pragma unroll
        for (int ks = 0; ks < 4; ++ks) {
            short8 bfr = *(const short8*)(Bbase + ks * 32);
            acc[t] = __builtin_amdgcn_mfma_f32_16x16x32_bf16(afr[ks], bfr, acc[t], 0, 0, 0);
        }
    }

    // epilogue: C/D layout col=lane&15, row=quad*4+reg
    #pragma unroll
    for (int t = 0; t < 13; ++t) {
        int col = nbase + t * 16 + m16;
        float bb = biasc[col];
        #pragma unroll
        for (int r = 0; r < 4; ++r) {
            int grow = row0 + wv * 16 + quad * 4 + r;
            if (grow >= NN) continue;
            float v = acc[t][r] + bb;
            if (col < 128)      el_mut[(size_t)grow * HF + col] = v;
            else if (col < 256) er_mut[(size_t)grow * HF + (col - 128)] = v;
            else if (col < 384) el_self[(size_t)grow * HF + (col - 256)] = v;
            else                out[(size_t)grow * OUTC + (col - 384)] = v;
        }
    }
}

// ---------------- edge scores + segment max ----------------
__global__ __launch_bounds__(256) void edge_score(
    const float* __restrict__ el_mut, const float* __restrict__ er_mut,
    const float* __restrict__ attn,
    const int* __restrict__ src, const int* __restrict__ dst,
    float* __restrict__ s_arr, unsigned* __restrict__ smax)
{
    int tid = threadIdx.x;
    long long e = (long long)blockIdx.x * 2 + (tid >> 7);
    if (e >= EE) return;
    int i = tid & 127;            // h*32 + f
    int h = i >> 5;
    int sn = src[e];
    int dn = dst[e];
    float v = el_mut[(long long)sn * HF + i] + er_mut[(long long)dn * HF + i];
    v = (v > 0.f) ? v : NEG_SLOPE * v;
    v *= attn[i];
    #pragma unroll
    for (int off = 16; off > 0; off >>= 1)
        v += __shfl_down(v, off, 32);
    if ((i & 31) == 0) {
        s_arr[e * HH + h] = v;
        atomicMax(&smax[(long long)dn * HH + h], enc_f(v));
    }
}

// ---------------- exp + denom ----------------
__global__ __launch_bounds__(256) void edge_exp(
    float* __restrict__ s_arr, const unsigned* __restrict__ smax,
    const int* __restrict__ dst, float* __restrict__ denom)
{
    long long idx = (long long)blockIdx.x * 256 + threadIdx.x;
    if (idx >= (long long)EE * HH) return;
    long long e = idx >> 2;
    int h = (int)(idx & 3);
    int dn = dst[e];
    float m = dec_f(smax[(long long)dn * HH + h]);
    float ex = __expf(s_arr[idx] - m);
    s_arr[idx] = ex;
    unsafeAtomicAdd(&denom[(long long)dn * HH + h], ex);
}

// ---------------- weighted aggregation (atomic scatter) ----------------
__global__ __launch_bounds__(256) void edge_agg(
    const float* __restrict__ el_self, const float* __restrict__ s_arr,
    const float* __restrict__ denom,
    const int* __restrict__ src, const int* __restrict__ dst,
    float* __restrict__ out)
{
    int tid = threadIdx.x;
    long long e = (long long)blockIdx.x * 2 + (tid >> 7);
    if (e >= EE) return;
    int i = tid & 127;
    int h = i >> 5;
    int sn = src[e];
    int dn = dst[e];
    float a = s_arr[e * HH + h] / denom[(long long)dn * HH + h];
    float contrib = el_self[(long long)sn * HF + i] * a;
    unsafeAtomicAdd(&out[(long long)dn * OUTC + FF + i], contrib);
}

extern "C" void kernel_launch(void* const* d_in, const int* in_sizes, int n_in,
                              void* d_out, int out_size, void* d_ws, size_t ws_size,
                              hipStream_t stream) {
    const float* feat   = (const float*)d_in[0];
    const float* W_src  = (const float*)d_in[1];
    const float* b_src  = (const float*)d_in[2];
    const float* W_dst  = (const float*)d_in[3];
    const float* b_dst  = (const float*)d_in[4];
    const float* W_self = (const float*)d_in[5];
    const float* b_self = (const float*)d_in[6];
    const float* W_lin  = (const float*)d_in[7];
    const float* b_lin  = (const float*)d_in[8];
    const float* attn   = (const float*)d_in[9];
    const int*   src    = (const int*)d_in[10];
    const int*   dst    = (const int*)d_in[11];
    float* out = (float*)d_out;

    // workspace carve-up
    float* el_mut  = (float*)d_ws;
    float* er_mut  = el_mut  + (size_t)NN * HF;
    float* el_self = er_mut  + (size_t)NN * HF;
    float* s_arr   = el_self + (size_t)NN * HF;            // E*H
    unsigned* smax = (unsigned*)(s_arr + (size_t)EE * HH); // N*H
    float* denom   = (float*)(smax + (size_t)NN * HH);     // N*H
    unsigned short* WbT = (unsigned short*)(denom + (size_t)NN * HH); // 416*128 bf16
    float* biasc   = (float*)(WbT + 416 * 128);            // 416 fp32

    // 1) init out/smax/denom
    {
        int blocks = (out_size + 255) / 256;
        init_kernel<<<blocks, 256, 0, stream>>>(out, smax, denom, out_size);
    }
    // 2) weight prep (bf16 transpose + bias concat)
    prep_weights<<<(416 * 128 + 255) / 256, 256, 0, stream>>>(
        W_src, b_src, W_dst, b_dst, W_self, b_self, W_lin, b_lin, WbT, biasc);
    // 3) MFMA projection GEMM
    {
        dim3 grid((NN + 63) / 64, 2);
        proj_gemm_mfma<<<grid, 256, 0, stream>>>(feat, WbT, biasc,
                                                 el_mut, er_mut, el_self, out);
    }
    // 4) edge scores + segment max
    edge_score<<<EE / 2, 256, 0, stream>>>(el_mut, er_mut, attn, src, dst, s_arr, smax);
    // 5) exp + denom
    edge_exp<<<(EE * HH) / 256, 256, 0, stream>>>(s_arr, smax, dst, denom);
    // 6) weighted aggregation
    edge_agg<<<EE / 2, 256, 0, stream>>>(el_self, s_arr, denom, src, dst, out);
}

// Round 3
// 471.308 us; speedup vs baseline: 5.7691x; 1.7423x over previous
//
#include <hip/hip_runtime.h>
#include <hip/hip_bf16.h>

// Problem constants (from reference)
#define NN 50000
#define EE 800000
#define INF_ 128
#define HH 4
#define FF 32
#define HF 128          // H*F
#define OUTC 160        // (H+1)*F per node
#define NEG_SLOPE 0.2f

typedef __attribute__((ext_vector_type(8))) short short8;
typedef __attribute__((ext_vector_type(4))) float f32x4;

// fp32 -> bf16 bits, round-to-nearest-even
__device__ __forceinline__ unsigned short f2bf(float f) {
    union { float f; unsigned u; } in; in.f = f;
    unsigned u = in.u;
    u += 0x7fffu + ((u >> 16) & 1u);
    return (unsigned short)(u >> 16);
}

// ---------------- CSR build ----------------
__global__ void zero_counts(int* __restrict__ counts) {
    int idx = blockIdx.x * blockDim.x + threadIdx.x;
    if (idx < NN) counts[idx] = 0;
}

__global__ void hist_kernel(const int* __restrict__ dst, int* __restrict__ counts) {
    int e = blockIdx.x * blockDim.x + threadIdx.x;
    if (e < EE) atomicAdd(&counts[dst[e]], 1);
}

// single-block exclusive scan over counts[NN] -> offsets, cursor
__global__ __launch_bounds__(1024) void scan_kernel(
    const int* __restrict__ counts, int* __restrict__ offsets, int* __restrict__ cursor)
{
    __shared__ int part[1024];
    const int t = threadIdx.x;
    const int per = (NN + 1023) / 1024;   // 49
    const int base = t * per;
    int s = 0;
    for (int k = 0; k < per; ++k) {
        int idx = base + k;
        if (idx < NN) s += counts[idx];
    }
    part[t] = s;
    __syncthreads();
    for (int off = 1; off < 1024; off <<= 1) {
        int v = (t >= off) ? part[t - off] : 0;
        __syncthreads();
        part[t] += v;
        __syncthreads();
    }
    int excl = part[t] - s;   // exclusive prefix of this thread's chunk
    for (int k = 0; k < per; ++k) {
        int idx = base + k;
        if (idx < NN) {
            offsets[idx] = excl;
            cursor[idx]  = excl;
            excl += counts[idx];
        }
    }
}

__global__ void scatter_kernel(const int* __restrict__ src, const int* __restrict__ dst,
                               int* __restrict__ cursor, int* __restrict__ srcbuck)
{
    int e = blockIdx.x * blockDim.x + threadIdx.x;
    if (e < EE) {
        int pos = atomicAdd(&cursor[dst[e]], 1);
        srcbuck[pos] = src[e];
    }
}

// ---------------- weight prep: concat + transpose + bf16 ----------------
__global__ __launch_bounds__(256) void prep_weights(
    const float* __restrict__ W0, const float* __restrict__ b0,
    const float* __restrict__ W1, const float* __restrict__ b1,
    const float* __restrict__ W2, const float* __restrict__ b2,
    const float* __restrict__ W3, const float* __restrict__ b3,
    unsigned short* __restrict__ WbT, float* __restrict__ biasc)
{
    int idx = blockIdx.x * 256 + threadIdx.x;   // 416*128 = 53248
    if (idx >= 416 * 128) return;
    int n = idx >> 7, k = idx & 127;
    float v;
    if (n < 128)      v = W0[k * 128 + n];
    else if (n < 256) v = W1[k * 128 + (n - 128)];
    else if (n < 384) v = W2[k * 128 + (n - 256)];
    else              v = W3[k * 32  + (n - 384)];
    WbT[n * 128 + k] = f2bf(v);
    if (idx < 416) {
        float bv;
        if (idx < 128)      bv = b0[idx];
        else if (idx < 256) bv = b1[idx - 128];
        else if (idx < 384) bv = b2[idx - 256];
        else                bv = b3[idx - 384];
        biasc[idx] = bv;
    }
}

// ---------------- bf16 MFMA projection GEMM ----------------
#define LSTRIDE 136
__global__ __launch_bounds__(256) void proj_gemm_mfma(
    const float* __restrict__ feat,
    const unsigned short* __restrict__ WbT,
    const float* __restrict__ biasc,
    float* __restrict__ el_mut, float* __restrict__ er_mut,
    float* __restrict__ el_self, float* __restrict__ out)
{
    __shared__ unsigned short As[64  * LSTRIDE];
    __shared__ unsigned short Bs[208 * LSTRIDE];

    const int tid  = threadIdx.x;
    const int row0 = blockIdx.x * 64;
    const int nbase = blockIdx.y * 208;

    #pragma unroll
    for (int it = 0; it < 8; ++it) {
        int f  = tid + it * 256;
        int r  = f >> 5;
        int k4 = f & 31;
        int grow = row0 + r;
        float4 v = make_float4(0.f, 0.f, 0.f, 0.f);
        if (grow < NN) v = ((const float4*)feat)[(size_t)grow * 32 + k4];
        unsigned p0 = (unsigned)f2bf(v.x) | ((unsigned)f2bf(v.y) << 16);
        unsigned p1 = (unsigned)f2bf(v.z) | ((unsigned)f2bf(v.w) << 16);
        uint2 pk; pk.x = p0; pk.y = p1;
        *(uint2*)&As[r * LSTRIDE + k4 * 4] = pk;
    }
    #pragma unroll
    for (int it = 0; it < 26; ++it) {
        int c  = tid + it * 256;
        int n  = c >> 5;
        int kc = c & 31;
        uint2 v = *(const uint2*)&WbT[(size_t)(nbase + n) * 128 + kc * 4];
        *(uint2*)&Bs[n * LSTRIDE + kc * 4] = v;
    }
    __syncthreads();

    const int wv   = tid >> 6;
    const int lane = tid & 63;
    const int m16  = lane & 15;
    const int quad = lane >> 4;

    f32x4 acc[13];
    #pragma unroll
    for (int t = 0; t < 13; ++t) acc[t] = (f32x4){0.f, 0.f, 0.f, 0.f};

    short8 afr[4];
    const unsigned short* Abase = &As[(wv * 16 + m16) * LSTRIDE + quad * 8];
    #pragma unroll
    for (int ks = 0; ks < 4; ++ks)
        afr[ks] = *(const short8*)(Abase + ks * 32);

    #pragma unroll
    for (int t = 0; t < 13; ++t) {
        const unsigned short* Bbase = &Bs[(t * 16 + m16) * LSTRIDE + quad * 8];
        #pragma unroll
        for (int ks = 0; ks < 4; ++ks) {
            short8 bfr = *(const short8*)(Bbase + ks * 32);
            acc[t] = __builtin_amdgcn_mfma_f32_16x16x32_bf16(afr[ks], bfr, acc[t], 0, 0, 0);
        }
    }

    #pragma unroll
    for (int t = 0; t < 13; ++t) {
        int col = nbase + t * 16 + m16;
        float bb = biasc[col];
        #pragma unroll
        for (int r = 0; r < 4; ++r) {
            int grow = row0 + wv * 16 + quad * 4 + r;
            if (grow >= NN) continue;
            float v = acc[t][r] + bb;
            if (col < 128)      el_mut[(size_t)grow * HF + col] = v;
            else if (col < 256) er_mut[(size_t)grow * HF + (col - 128)] = v;
            else if (col < 384) el_self[(size_t)grow * HF + (col - 256)] = v;
            else                out[(size_t)grow * OUTC + (col - 384)] = v;
        }
    }
}

// ---------------- fused per-node score + online softmax + aggregation ----------------
// one 128-thread block per dst node; thread i owns channel i = h*32+f
__device__ __forceinline__ void agg_step(
    float a_el, float c_el, float er, float at,
    float& m, float& l, float& acc)
{
    float v = a_el + er;
    v = (v > 0.f) ? v : NEG_SLOPE * v;
    v *= at;
    #pragma unroll
    for (int off = 1; off < 32; off <<= 1)
        v += __shfl_xor(v, off, 32);      // all 32 lanes of the head get s
    float s = v;
    float mn = fmaxf(m, s);
    float scale = __expf(m - mn);
    float p = __expf(s - mn);
    l = l * scale + p;
    acc = acc * scale + p * c_el;
    m = mn;
}

__global__ __launch_bounds__(128) void node_agg(
    const float* __restrict__ el_mut, const float* __restrict__ er_mut,
    const float* __restrict__ el_self, const float* __restrict__ attn,
    const int* __restrict__ offsets, const int* __restrict__ counts,
    const int* __restrict__ srcbuck, float* __restrict__ out)
{
    const int n = blockIdx.x;
    const int i = threadIdx.x;           // 0..127, h = i>>5
    const float er = er_mut[(size_t)n * HF + i];
    const float at = attn[i];
    const int beg = offsets[n];
    const int deg = counts[n];

    float m = -INFINITY, l = 0.f, acc = 0.f;

    int j = 0;
    for (; j + 1 < deg; j += 2) {
        int sn0 = srcbuck[beg + j];
        int sn1 = srcbuck[beg + j + 1];
        float a0 = el_mut[(size_t)sn0 * HF + i];
        float c0 = el_self[(size_t)sn0 * HF + i];
        float a1 = el_mut[(size_t)sn1 * HF + i];
        float c1 = el_self[(size_t)sn1 * HF + i];
        agg_step(a0, c0, er, at, m, l, acc);
        agg_step(a1, c1, er, at, m, l, acc);
    }
    if (j < deg) {
        int sn = srcbuck[beg + j];
        float a0 = el_mut[(size_t)sn * HF + i];
        float c0 = el_self[(size_t)sn * HF + i];
        agg_step(a0, c0, er, at, m, l, acc);
    }

    float r = (l > 0.f) ? (acc / l) : 0.f;
    out[(size_t)n * OUTC + FF + i] = r;
}

extern "C" void kernel_launch(void* const* d_in, const int* in_sizes, int n_in,
                              void* d_out, int out_size, void* d_ws, size_t ws_size,
                              hipStream_t stream) {
    const float* feat   = (const float*)d_in[0];
    const float* W_src  = (const float*)d_in[1];
    const float* b_src  = (const float*)d_in[2];
    const float* W_dst  = (const float*)d_in[3];
    const float* b_dst  = (const float*)d_in[4];
    const float* W_self = (const float*)d_in[5];
    const float* b_self = (const float*)d_in[6];
    const float* W_lin  = (const float*)d_in[7];
    const float* b_lin  = (const float*)d_in[8];
    const float* attn   = (const float*)d_in[9];
    const int*   src    = (const int*)d_in[10];
    const int*   dst    = (const int*)d_in[11];
    float* out = (float*)d_out;

    // workspace carve-up
    float* el_mut  = (float*)d_ws;
    float* er_mut  = el_mut  + (size_t)NN * HF;
    float* el_self = er_mut  + (size_t)NN * HF;
    int*   counts  = (int*)(el_self + (size_t)NN * HF);
    int*   offsets = counts  + NN;
    int*   cursor  = offsets + NN;
    int*   srcbuck = cursor  + NN;                         // E ints
    unsigned short* WbT = (unsigned short*)(srcbuck + EE); // 416*128 bf16
    float* biasc   = (float*)(WbT + 416 * 128);            // 416 fp32

    // CSR build
    zero_counts<<<(NN + 255) / 256, 256, 0, stream>>>(counts);
    hist_kernel<<<(EE + 255) / 256, 256, 0, stream>>>(dst, counts);
    scan_kernel<<<1, 1024, 0, stream>>>(counts, offsets, cursor);
    scatter_kernel<<<(EE + 255) / 256, 256, 0, stream>>>(src, dst, cursor, srcbuck);

    // projections
    prep_weights<<<(416 * 128 + 255) / 256, 256, 0, stream>>>(
        W_src, b_src, W_dst, b_dst, W_self, b_self, W_lin, b_lin, WbT, biasc);
    {
        dim3 grid((NN + 63) / 64, 2);
        proj_gemm_mfma<<<grid, 256, 0, stream>>>(feat, WbT, biasc,
                                                 el_mut, er_mut, el_self, out);
    }

    // fused edge phase
    node_agg<<<NN, 128, 0, stream>>>(el_mut, er_mut, el_self, attn,
                                     offsets, counts, srcbuck, out);
}

// Round 4
// 347.570 us; speedup vs baseline: 7.8229x; 1.3560x over previous
//
#include <hip/hip_runtime.h>
#include <hip/hip_bf16.h>

// Problem constants (from reference)
#define NN 50000
#define EE 800000
#define INF_ 128
#define HH 4
#define FF 32
#define HF 128          // H*F
#define OUTC 160        // (H+1)*F per node
#define NEG_SLOPE 0.2f

#define SCAN_B 196      // ceil(50000/256)

typedef __attribute__((ext_vector_type(8))) short short8;
typedef __attribute__((ext_vector_type(4))) float f32x4;

// fp32 -> bf16 bits, round-to-nearest-even
__device__ __forceinline__ unsigned short f2bf(float f) {
    union { float f; unsigned u; } in; in.f = f;
    unsigned u = in.u;
    u += 0x7fffu + ((u >> 16) & 1u);
    return (unsigned short)(u >> 16);
}

// ---------------- CSR build ----------------
__global__ void zero_counts(int* __restrict__ counts) {
    int idx = blockIdx.x * blockDim.x + threadIdx.x;
    if (idx < NN) counts[idx] = 0;
}

__global__ void hist_kernel(const int* __restrict__ dst, int* __restrict__ counts) {
    int e = blockIdx.x * blockDim.x + threadIdx.x;
    if (e < EE) atomicAdd(&counts[dst[e]], 1);
}

// phase 1: per-block sum of 256 counts
__global__ __launch_bounds__(256) void scan_bsum(
    const int* __restrict__ counts, int* __restrict__ bsum)
{
    __shared__ int sh[256];
    int t = threadIdx.x;
    int idx = blockIdx.x * 256 + t;
    sh[t] = (idx < NN) ? counts[idx] : 0;
    __syncthreads();
    #pragma unroll
    for (int off = 128; off > 0; off >>= 1) {
        if (t < off) sh[t] += sh[t + off];
        __syncthreads();
    }
    if (t == 0) bsum[blockIdx.x] = sh[0];
}

// phase 2: single-block exclusive scan of SCAN_B partials
__global__ __launch_bounds__(256) void scan_top(
    const int* __restrict__ bsum, int* __restrict__ bprefix)
{
    __shared__ int sh[256];
    int t = threadIdx.x;
    int v = (t < SCAN_B) ? bsum[t] : 0;
    sh[t] = v;
    __syncthreads();
    #pragma unroll
    for (int off = 1; off < 256; off <<= 1) {
        int u = (t >= off) ? sh[t - off] : 0;
        __syncthreads();
        sh[t] += u;
        __syncthreads();
    }
    if (t < SCAN_B) bprefix[t] = sh[t] - v;   // exclusive
}

// phase 3: per-block exclusive scan + block prefix -> offsets, cursor
__global__ __launch_bounds__(256) void scan_final(
    const int* __restrict__ counts, const int* __restrict__ bprefix,
    int* __restrict__ offsets, int* __restrict__ cursor)
{
    __shared__ int sh[256];
    int t = threadIdx.x;
    int idx = blockIdx.x * 256 + t;
    int v = (idx < NN) ? counts[idx] : 0;
    sh[t] = v;
    __syncthreads();
    #pragma unroll
    for (int off = 1; off < 256; off <<= 1) {
        int u = (t >= off) ? sh[t - off] : 0;
        __syncthreads();
        sh[t] += u;
        __syncthreads();
    }
    if (idx < NN) {
        int excl = sh[t] - v + bprefix[blockIdx.x];
        offsets[idx] = excl;
        cursor[idx]  = excl;
    }
}

__global__ void scatter_kernel(const int* __restrict__ src, const int* __restrict__ dst,
                               int* __restrict__ cursor, int* __restrict__ srcbuck)
{
    int e = blockIdx.x * blockDim.x + threadIdx.x;
    if (e < EE) {
        int pos = atomicAdd(&cursor[dst[e]], 1);
        srcbuck[pos] = src[e];
    }
}

// ---------------- weight prep: concat + transpose + bf16 ----------------
__global__ __launch_bounds__(256) void prep_weights(
    const float* __restrict__ W0, const float* __restrict__ b0,
    const float* __restrict__ W1, const float* __restrict__ b1,
    const float* __restrict__ W2, const float* __restrict__ b2,
    const float* __restrict__ W3, const float* __restrict__ b3,
    unsigned short* __restrict__ WbT, float* __restrict__ biasc)
{
    int idx = blockIdx.x * 256 + threadIdx.x;   // 416*128 = 53248
    if (idx >= 416 * 128) return;
    int n = idx >> 7, k = idx & 127;
    float v;
    if (n < 128)      v = W0[k * 128 + n];
    else if (n < 256) v = W1[k * 128 + (n - 128)];
    else if (n < 384) v = W2[k * 128 + (n - 256)];
    else              v = W3[k * 32  + (n - 384)];
    WbT[n * 128 + k] = f2bf(v);
    if (idx < 416) {
        float bv;
        if (idx < 128)      bv = b0[idx];
        else if (idx < 256) bv = b1[idx - 128];
        else if (idx < 384) bv = b2[idx - 256];
        else                bv = b3[idx - 384];
        biasc[idx] = bv;
    }
}

// ---------------- bf16 MFMA projection GEMM ----------------
#define LSTRIDE 136
__global__ __launch_bounds__(256) void proj_gemm_mfma(
    const float* __restrict__ feat,
    const unsigned short* __restrict__ WbT,
    const float* __restrict__ biasc,
    float* __restrict__ el_mut, float* __restrict__ er_mut,
    float* __restrict__ el_self, float* __restrict__ out)
{
    __shared__ unsigned short As[64  * LSTRIDE];
    __shared__ unsigned short Bs[208 * LSTRIDE];

    const int tid  = threadIdx.x;
    const int row0 = blockIdx.x * 64;
    const int nbase = blockIdx.y * 208;

    #pragma unroll
    for (int it = 0; it < 8; ++it) {
        int f  = tid + it * 256;
        int r  = f >> 5;
        int k4 = f & 31;
        int grow = row0 + r;
        float4 v = make_float4(0.f, 0.f, 0.f, 0.f);
        if (grow < NN) v = ((const float4*)feat)[(size_t)grow * 32 + k4];
        unsigned p0 = (unsigned)f2bf(v.x) | ((unsigned)f2bf(v.y) << 16);
        unsigned p1 = (unsigned)f2bf(v.z) | ((unsigned)f2bf(v.w) << 16);
        uint2 pk; pk.x = p0; pk.y = p1;
        *(uint2*)&As[r * LSTRIDE + k4 * 4] = pk;
    }
    #pragma unroll
    for (int it = 0; it < 26; ++it) {
        int c  = tid + it * 256;
        int n  = c >> 5;
        int kc = c & 31;
        uint2 v = *(const uint2*)&WbT[(size_t)(nbase + n) * 128 + kc * 4];
        *(uint2*)&Bs[n * LSTRIDE + kc * 4] = v;
    }
    __syncthreads();

    const int wv   = tid >> 6;
    const int lane = tid & 63;
    const int m16  = lane & 15;
    const int quad = lane >> 4;

    f32x4 acc[13];
    #pragma unroll
    for (int t = 0; t < 13; ++t) acc[t] = (f32x4){0.f, 0.f, 0.f, 0.f};

    short8 afr[4];
    const unsigned short* Abase = &As[(wv * 16 + m16) * LSTRIDE + quad * 8];
    #pragma unroll
    for (int ks = 0; ks < 4; ++ks)
        afr[ks] = *(const short8*)(Abase + ks * 32);

    #pragma unroll
    for (int t = 0; t < 13; ++t) {
        const unsigned short* Bbase = &Bs[(t * 16 + m16) * LSTRIDE + quad * 8];
        #pragma unroll
        for (int ks = 0; ks < 4; ++ks) {
            short8 bfr = *(const short8*)(Bbase + ks * 32);
            acc[t] = __builtin_amdgcn_mfma_f32_16x16x32_bf16(afr[ks], bfr, acc[t], 0, 0, 0);
        }
    }

    #pragma unroll
    for (int t = 0; t < 13; ++t) {
        int col = nbase + t * 16 + m16;
        float bb = biasc[col];
        #pragma unroll
        for (int r = 0; r < 4; ++r) {
            int grow = row0 + wv * 16 + quad * 4 + r;
            if (grow >= NN) continue;
            float v = acc[t][r] + bb;
            if (col < 128)      el_mut[(size_t)grow * HF + col] = v;
            else if (col < 256) er_mut[(size_t)grow * HF + (col - 128)] = v;
            else if (col < 384) el_self[(size_t)grow * HF + (col - 256)] = v;
            else                out[(size_t)grow * OUTC + (col - 384)] = v;
        }
    }
}

// ---------------- fused per-node score + online softmax + aggregation ----------------
__device__ __forceinline__ void agg_step(
    float a_el, float c_el, float er, float at,
    float& m, float& l, float& acc)
{
    float v = a_el + er;
    v = (v > 0.f) ? v : NEG_SLOPE * v;
    v *= at;
    #pragma unroll
    for (int off = 1; off < 32; off <<= 1)
        v += __shfl_xor(v, off, 32);
    float s = v;
    float mn = fmaxf(m, s);
    float scale = __expf(m - mn);
    float p = __expf(s - mn);
    l = l * scale + p;
    acc = acc * scale + p * c_el;
    m = mn;
}

__global__ __launch_bounds__(128) void node_agg(
    const float* __restrict__ el_mut, const float* __restrict__ er_mut,
    const float* __restrict__ el_self, const float* __restrict__ attn,
    const int* __restrict__ offsets, const int* __restrict__ counts,
    const int* __restrict__ srcbuck, float* __restrict__ out)
{
    const int n = blockIdx.x;
    const int i = threadIdx.x;
    const float er = er_mut[(size_t)n * HF + i];
    const float at = attn[i];
    const int beg = offsets[n];
    const int deg = counts[n];

    float m = -INFINITY, l = 0.f, acc = 0.f;

    int j = 0;
    for (; j + 1 < deg; j += 2) {
        int sn0 = srcbuck[beg + j];
        int sn1 = srcbuck[beg + j + 1];
        float a0 = el_mut[(size_t)sn0 * HF + i];
        float c0 = el_self[(size_t)sn0 * HF + i];
        float a1 = el_mut[(size_t)sn1 * HF + i];
        float c1 = el_self[(size_t)sn1 * HF + i];
        agg_step(a0, c0, er, at, m, l, acc);
        agg_step(a1, c1, er, at, m, l, acc);
    }
    if (j < deg) {
        int sn = srcbuck[beg + j];
        float a0 = el_mut[(size_t)sn * HF + i];
        float c0 = el_self[(size_t)sn * HF + i];
        agg_step(a0, c0, er, at, m, l, acc);
    }

    float r = (l > 0.f) ? (acc / l) : 0.f;
    out[(size_t)n * OUTC + FF + i] = r;
}

extern "C" void kernel_launch(void* const* d_in, const int* in_sizes, int n_in,
                              void* d_out, int out_size, void* d_ws, size_t ws_size,
                              hipStream_t stream) {
    const float* feat   = (const float*)d_in[0];
    const float* W_src  = (const float*)d_in[1];
    const float* b_src  = (const float*)d_in[2];
    const float* W_dst  = (const float*)d_in[3];
    const float* b_dst  = (const float*)d_in[4];
    const float* W_self = (const float*)d_in[5];
    const float* b_self = (const float*)d_in[6];
    const float* W_lin  = (const float*)d_in[7];
    const float* b_lin  = (const float*)d_in[8];
    const float* attn   = (const float*)d_in[9];
    const int*   src    = (const int*)d_in[10];
    const int*   dst    = (const int*)d_in[11];
    float* out = (float*)d_out;

    // workspace carve-up
    float* el_mut  = (float*)d_ws;
    float* er_mut  = el_mut  + (size_t)NN * HF;
    float* el_self = er_mut  + (size_t)NN * HF;
    int*   counts  = (int*)(el_self + (size_t)NN * HF);
    int*   offsets = counts  + NN;
    int*   cursor  = offsets + NN;
    int*   srcbuck = cursor  + NN;                         // E ints
    int*   bsum    = srcbuck + EE;                         // SCAN_B
    int*   bprefix = bsum    + SCAN_B;                     // SCAN_B
    unsigned short* WbT = (unsigned short*)(bprefix + SCAN_B); // 416*128 bf16
    float* biasc   = (float*)(WbT + 416 * 128);            // 416 fp32

    // CSR build (hierarchical scan)
    zero_counts<<<(NN + 255) / 256, 256, 0, stream>>>(counts);
    hist_kernel<<<(EE + 255) / 256, 256, 0, stream>>>(dst, counts);
    scan_bsum <<<SCAN_B, 256, 0, stream>>>(counts, bsum);
    scan_top  <<<1, 256, 0, stream>>>(bsum, bprefix);
    scan_final<<<SCAN_B, 256, 0, stream>>>(counts, bprefix, offsets, cursor);
    scatter_kernel<<<(EE + 255) / 256, 256, 0, stream>>>(src, dst, cursor, srcbuck);

    // projections
    prep_weights<<<(416 * 128 + 255) / 256, 256, 0, stream>>>(
        W_src, b_src, W_dst, b_dst, W_self, b_self, W_lin, b_lin, WbT, biasc);
    {
        dim3 grid((NN + 63) / 64, 2);
        proj_gemm_mfma<<<grid, 256, 0, stream>>>(feat, WbT, biasc,
                                                 el_mut, er_mut, el_self, out);
    }

    // fused edge phase
    node_agg<<<NN, 128, 0, stream>>>(el_mut, er_mut, el_self, attn,
                                     offsets, counts, srcbuck, out);
}

// Round 5
// 296.738 us; speedup vs baseline: 9.1630x; 1.1713x over previous
//
#include <hip/hip_runtime.h>
#include <hip/hip_bf16.h>

// Problem constants (from reference)
#define NN 50000
#define EE 800000
#define INF_ 128
#define HH 4
#define FF 32
#define HF 128          // H*F
#define OUTC 160        // (H+1)*F per node
#define NEG_SLOPE 0.2f

#define SCAN_B 196      // ceil(50000/256)

typedef __attribute__((ext_vector_type(8))) short short8;
typedef __attribute__((ext_vector_type(4))) float f32x4;

// fp32 -> bf16 bits, round-to-nearest-even
__device__ __forceinline__ unsigned short f2bf(float f) {
    union { float f; unsigned u; } in; in.f = f;
    unsigned u = in.u;
    u += 0x7fffu + ((u >> 16) & 1u);
    return (unsigned short)(u >> 16);
}
__device__ __forceinline__ float bflo(unsigned w) {   // low ushort as bf16 -> f32
    return __uint_as_float(w << 16);
}
__device__ __forceinline__ float bfhi(unsigned w) {   // high ushort as bf16 -> f32
    return __uint_as_float(w & 0xffff0000u);
}

// ---------------- CSR build ----------------
__global__ void zero_counts(int* __restrict__ counts) {
    int idx = blockIdx.x * blockDim.x + threadIdx.x;
    if (idx < NN) counts[idx] = 0;
}

// histogram; atomic return value = rank of edge within its dst bucket
__global__ void hist_kernel(const int* __restrict__ dst, int* __restrict__ counts,
                            int* __restrict__ rank) {
    int e = blockIdx.x * blockDim.x + threadIdx.x;
    if (e < EE) rank[e] = atomicAdd(&counts[dst[e]], 1);
}

// phase 1: per-block sum of 256 counts
__global__ __launch_bounds__(256) void scan_bsum(
    const int* __restrict__ counts, int* __restrict__ bsum)
{
    __shared__ int sh[256];
    int t = threadIdx.x;
    int idx = blockIdx.x * 256 + t;
    sh[t] = (idx < NN) ? counts[idx] : 0;
    __syncthreads();
    #pragma unroll
    for (int off = 128; off > 0; off >>= 1) {
        if (t < off) sh[t] += sh[t + off];
        __syncthreads();
    }
    if (t == 0) bsum[blockIdx.x] = sh[0];
}

// phase 2: single-block exclusive scan of SCAN_B partials
__global__ __launch_bounds__(256) void scan_top(
    const int* __restrict__ bsum, int* __restrict__ bprefix)
{
    __shared__ int sh[256];
    int t = threadIdx.x;
    int v = (t < SCAN_B) ? bsum[t] : 0;
    sh[t] = v;
    __syncthreads();
    #pragma unroll
    for (int off = 1; off < 256; off <<= 1) {
        int u = (t >= off) ? sh[t - off] : 0;
        __syncthreads();
        sh[t] += u;
        __syncthreads();
    }
    if (t < SCAN_B) bprefix[t] = sh[t] - v;   // exclusive
}

// phase 3: per-block exclusive scan + block prefix -> offsets
__global__ __launch_bounds__(256) void scan_final(
    const int* __restrict__ counts, const int* __restrict__ bprefix,
    int* __restrict__ offsets)
{
    __shared__ int sh[256];
    int t = threadIdx.x;
    int idx = blockIdx.x * 256 + t;
    int v = (idx < NN) ? counts[idx] : 0;
    sh[t] = v;
    __syncthreads();
    #pragma unroll
    for (int off = 1; off < 256; off <<= 1) {
        int u = (t >= off) ? sh[t - off] : 0;
        __syncthreads();
        sh[t] += u;
        __syncthreads();
    }
    if (idx < NN) offsets[idx] = sh[t] - v + bprefix[blockIdx.x];
}

// atomic-free scatter using precomputed ranks
__global__ void scatter_kernel(const int* __restrict__ src, const int* __restrict__ dst,
                               const int* __restrict__ offsets, const int* __restrict__ rank,
                               int* __restrict__ srcbuck)
{
    int e = blockIdx.x * blockDim.x + threadIdx.x;
    if (e < EE) srcbuck[offsets[dst[e]] + rank[e]] = src[e];
}

// ---------------- weight prep: concat + transpose + bf16 ----------------
__global__ __launch_bounds__(256) void prep_weights(
    const float* __restrict__ W0, const float* __restrict__ b0,
    const float* __restrict__ W1, const float* __restrict__ b1,
    const float* __restrict__ W2, const float* __restrict__ b2,
    const float* __restrict__ W3, const float* __restrict__ b3,
    unsigned short* __restrict__ WbT, float* __restrict__ biasc)
{
    int idx = blockIdx.x * 256 + threadIdx.x;   // 416*128 = 53248
    if (idx >= 416 * 128) return;
    int n = idx >> 7, k = idx & 127;
    float v;
    if (n < 128)      v = W0[k * 128 + n];
    else if (n < 256) v = W1[k * 128 + (n - 128)];
    else if (n < 384) v = W2[k * 128 + (n - 256)];
    else              v = W3[k * 32  + (n - 384)];
    WbT[n * 128 + k] = f2bf(v);
    if (idx < 416) {
        float bv;
        if (idx < 128)      bv = b0[idx];
        else if (idx < 256) bv = b1[idx - 128];
        else if (idx < 384) bv = b2[idx - 256];
        else                bv = b3[idx - 384];
        biasc[idx] = bv;
    }
}

// ---------------- bf16 MFMA projection GEMM ----------------
// epilogue: cols 0-127 -> pack lo (el_mut bf16), 128-255 -> er_mut fp32,
//           256-383 -> pack hi (el_self bf16), 384-415 -> out feat_lin
#define LSTRIDE 136
__global__ __launch_bounds__(256) void proj_gemm_mfma(
    const float* __restrict__ feat,
    const unsigned short* __restrict__ WbT,
    const float* __restrict__ biasc,
    unsigned short* __restrict__ packs,   // as ushort: [n][c][2] = {mut, self}
    float* __restrict__ er_mut, float* __restrict__ out)
{
    __shared__ unsigned short As[64  * LSTRIDE];
    __shared__ unsigned short Bs[208 * LSTRIDE];

    const int tid  = threadIdx.x;
    const int row0 = blockIdx.x * 64;
    const int nbase = blockIdx.y * 208;

    #pragma unroll
    for (int it = 0; it < 8; ++it) {
        int f  = tid + it * 256;
        int r  = f >> 5;
        int k4 = f & 31;
        int grow = row0 + r;
        float4 v = make_float4(0.f, 0.f, 0.f, 0.f);
        if (grow < NN) v = ((const float4*)feat)[(size_t)grow * 32 + k4];
        unsigned p0 = (unsigned)f2bf(v.x) | ((unsigned)f2bf(v.y) << 16);
        unsigned p1 = (unsigned)f2bf(v.z) | ((unsigned)f2bf(v.w) << 16);
        uint2 pk; pk.x = p0; pk.y = p1;
        *(uint2*)&As[r * LSTRIDE + k4 * 4] = pk;
    }
    #pragma unroll
    for (int it = 0; it < 26; ++it) {
        int c  = tid + it * 256;
        int n  = c >> 5;
        int kc = c & 31;
        uint2 v = *(const uint2*)&WbT[(size_t)(nbase + n) * 128 + kc * 4];
        *(uint2*)&Bs[n * LSTRIDE + kc * 4] = v;
    }
    __syncthreads();

    const int wv   = tid >> 6;
    const int lane = tid & 63;
    const int m16  = lane & 15;
    const int quad = lane >> 4;

    f32x4 acc[13];
    #pragma unroll
    for (int t = 0; t < 13; ++t) acc[t] = (f32x4){0.f, 0.f, 0.f, 0.f};

    short8 afr[4];
    const unsigned short* Abase = &As[(wv * 16 + m16) * LSTRIDE + quad * 8];
    #pragma unroll
    for (int ks = 0; ks < 4; ++ks)
        afr[ks] = *(const short8*)(Abase + ks * 32);

    #pragma unroll
    for (int t = 0; t < 13; ++t) {
        const unsigned short* Bbase = &Bs[(t * 16 + m16) * LSTRIDE + quad * 8];
        #pragma unroll
        for (int ks = 0; ks < 4; ++ks) {
            short8 bfr = *(const short8*)(Bbase + ks * 32);
            acc[t] = __builtin_amdgcn_mfma_f32_16x16x32_bf16(afr[ks], bfr, acc[t], 0, 0, 0);
        }
    }

    #pragma unroll
    for (int t = 0; t < 13; ++t) {
        int col = nbase + t * 16 + m16;
        float bb = biasc[col];
        #pragma unroll
        for (int r = 0; r < 4; ++r) {
            int grow = row0 + wv * 16 + quad * 4 + r;
            if (grow >= NN) continue;
            float v = acc[t][r] + bb;
            if (col < 128)      packs[((size_t)grow * HF + col) * 2]       = f2bf(v);
            else if (col < 256) er_mut[(size_t)grow * HF + (col - 128)] = v;
            else if (col < 384) packs[((size_t)grow * HF + (col - 256)) * 2 + 1] = f2bf(v);
            else                out[(size_t)grow * OUTC + (col - 384)] = v;
        }
    }
}

// ---------------- fused per-node score + softmax (no-max) + aggregation ----------------
__device__ __forceinline__ float edge_term(unsigned w, float er, float at, float& c) {
    float a = bflo(w);
    c = bfhi(w);
    float v = a + er;
    v = (v > 0.f) ? v : NEG_SLOPE * v;
    return v * at;
}

__global__ __launch_bounds__(128) void node_agg(
    const unsigned* __restrict__ pack, const float* __restrict__ er_mut,
    const float* __restrict__ attn,
    const int* __restrict__ offsets, const int* __restrict__ counts,
    const int* __restrict__ srcbuck, float* __restrict__ out)
{
    const int n = blockIdx.x;
    const int i = threadIdx.x;           // 0..127, h = i>>5
    const float er = er_mut[(size_t)n * HF + i];
    const float at = attn[i];
    const int beg = offsets[n];
    const int deg = counts[n];

    float l0 = 0.f, l1 = 0.f, acc0 = 0.f, acc1 = 0.f;

    int j = 0;
    for (; j + 3 < deg; j += 4) {
        int sn0 = srcbuck[beg + j];
        int sn1 = srcbuck[beg + j + 1];
        int sn2 = srcbuck[beg + j + 2];
        int sn3 = srcbuck[beg + j + 3];
        unsigned w0 = pack[(size_t)sn0 * HF + i];
        unsigned w1 = pack[(size_t)sn1 * HF + i];
        unsigned w2 = pack[(size_t)sn2 * HF + i];
        unsigned w3 = pack[(size_t)sn3 * HF + i];
        float c0, c1, c2, c3;
        float v0 = edge_term(w0, er, at, c0);
        float v1 = edge_term(w1, er, at, c1);
        float v2 = edge_term(w2, er, at, c2);
        float v3 = edge_term(w3, er, at, c3);
        #pragma unroll
        for (int off = 1; off < 32; off <<= 1) {
            v0 += __shfl_xor(v0, off, 32);
            v1 += __shfl_xor(v1, off, 32);
            v2 += __shfl_xor(v2, off, 32);
            v3 += __shfl_xor(v3, off, 32);
        }
        float p0 = __expf(v0), p1 = __expf(v1), p2 = __expf(v2), p3 = __expf(v3);
        l0 += p0 + p2; l1 += p1 + p3;
        acc0 = fmaf(p0, c0, acc0); acc1 = fmaf(p1, c1, acc1);
        acc0 = fmaf(p2, c2, acc0); acc1 = fmaf(p3, c3, acc1);
    }
    for (; j < deg; ++j) {
        int sn = srcbuck[beg + j];
        unsigned w = pack[(size_t)sn * HF + i];
        float c;
        float v = edge_term(w, er, at, c);
        #pragma unroll
        for (int off = 1; off < 32; off <<= 1)
            v += __shfl_xor(v, off, 32);
        float p = __expf(v);
        l0 += p;
        acc0 = fmaf(p, c, acc0);
    }

    float l = l0 + l1;
    float acc = acc0 + acc1;
    float r = (l > 0.f) ? (acc / l) : 0.f;
    out[(size_t)n * OUTC + FF + i] = r;
}

extern "C" void kernel_launch(void* const* d_in, const int* in_sizes, int n_in,
                              void* d_out, int out_size, void* d_ws, size_t ws_size,
                              hipStream_t stream) {
    const float* feat   = (const float*)d_in[0];
    const float* W_src  = (const float*)d_in[1];
    const float* b_src  = (const float*)d_in[2];
    const float* W_dst  = (const float*)d_in[3];
    const float* b_dst  = (const float*)d_in[4];
    const float* W_self = (const float*)d_in[5];
    const float* b_self = (const float*)d_in[6];
    const float* W_lin  = (const float*)d_in[7];
    const float* b_lin  = (const float*)d_in[8];
    const float* attn   = (const float*)d_in[9];
    const int*   src    = (const int*)d_in[10];
    const int*   dst    = (const int*)d_in[11];
    float* out = (float*)d_out;

    // workspace carve-up
    unsigned* pack = (unsigned*)d_ws;                      // N*HF uints (bf16 mut|self)
    float* er_mut  = (float*)(pack + (size_t)NN * HF);     // N*HF fp32
    int*   counts  = (int*)(er_mut + (size_t)NN * HF);
    int*   offsets = counts  + NN;
    int*   rank    = offsets + NN;                         // E ints
    int*   srcbuck = rank    + EE;                         // E ints
    int*   bsum    = srcbuck + EE;                         // SCAN_B
    int*   bprefix = bsum    + SCAN_B;                     // SCAN_B
    unsigned short* WbT = (unsigned short*)(bprefix + SCAN_B); // 416*128 bf16
    float* biasc   = (float*)(WbT + 416 * 128);            // 416 fp32

    // CSR build (hierarchical scan, atomic-free scatter)
    zero_counts<<<(NN + 255) / 256, 256, 0, stream>>>(counts);
    hist_kernel<<<(EE + 255) / 256, 256, 0, stream>>>(dst, counts, rank);
    scan_bsum <<<SCAN_B, 256, 0, stream>>>(counts, bsum);
    scan_top  <<<1, 256, 0, stream>>>(bsum, bprefix);
    scan_final<<<SCAN_B, 256, 0, stream>>>(counts, bprefix, offsets);
    scatter_kernel<<<(EE + 255) / 256, 256, 0, stream>>>(src, dst, offsets, rank, srcbuck);

    // projections
    prep_weights<<<(416 * 128 + 255) / 256, 256, 0, stream>>>(
        W_src, b_src, W_dst, b_dst, W_self, b_self, W_lin, b_lin, WbT, biasc);
    {
        dim3 grid((NN + 63) / 64, 2);
        proj_gemm_mfma<<<grid, 256, 0, stream>>>(feat, WbT, biasc,
                                                 (unsigned short*)pack, er_mut, out);
    }

    // fused edge phase
    node_agg<<<NN, 128, 0, stream>>>(pack, er_mut, attn,
                                     offsets, counts, srcbuck, out);
}